// Round 4
// baseline (10539.510 us; speedup 1.0000x reference)
//
#include <hip/hip_runtime.h>

#define HID 6
#define HS  8                   // padded row stride (floats) for h and ea_perm
#define NUM_GRAPHS 1000
#define SCAN_B 1024
#define NDB 64                  // degree buckets (exact degree, clamped)

// ===========================================================================
// pad x (N x 6) -> hX (N x 8)
// ===========================================================================
__global__ void pad_kernel(const float* __restrict__ x, float* __restrict__ hX, int N) {
    int i = blockIdx.x * blockDim.x + threadIdx.x;
    if (i >= N) return;
    const float2* s = (const float2*)(x + (size_t)i * HID);
    float2 a = s[0], b = s[1], c = s[2];
    float4* o = (float4*)(hX + (size_t)i * HS);
    o[0] = make_float4(a.x, a.y, b.x, b.y);
    o[1] = make_float4(c.x, c.y, 0.f, 0.f);
}

// ===========================================================================
// degree histogram
// ===========================================================================
__global__ void hist_kernel(const int* __restrict__ dst, int* __restrict__ deg, int E) {
    long i = ((long)blockIdx.x * blockDim.x + threadIdx.x) * 4;
    if (i + 4 <= E) {
        int4 v = *(const int4*)(dst + i);
        atomicAdd(&deg[v.x], 1);
        atomicAdd(&deg[v.y], 1);
        atomicAdd(&deg[v.z], 1);
        atomicAdd(&deg[v.w], 1);
    } else {
        for (long e = i; e < E; ++e) atomicAdd(&deg[dst[e]], 1);
    }
}

// in-place exclusive scan within 1024-blocks
__global__ void scan_block_kernel(int* __restrict__ data, int* __restrict__ blockSums, int N) {
    __shared__ int tmp[SCAN_B];
    int t = threadIdx.x;
    int i = blockIdx.x * SCAN_B + t;
    int v = (i < N) ? data[i] : 0;
    tmp[t] = v;
    __syncthreads();
    for (int off = 1; off < SCAN_B; off <<= 1) {
        int a = (t >= off) ? tmp[t - off] : 0;
        __syncthreads();
        tmp[t] += a;
        __syncthreads();
    }
    if (i < N) data[i] = tmp[t] - v;
    if (blockSums && t == SCAN_B - 1) blockSums[blockIdx.x] = tmp[SCAN_B - 1];
}

__global__ void scan_finish_kernel(const int* __restrict__ scanned,
                                   const int* __restrict__ blockOffsets,
                                   int* __restrict__ rowStart, int* __restrict__ cursor,
                                   int N, int E) {
    int i = blockIdx.x * blockDim.x + threadIdx.x;
    if (i < N) {
        int v = scanned[i] + blockOffsets[i >> 10];
        rowStart[i] = v;
        cursor[i] = v;
    }
    if (i == 0) rowStart[N] = E;
}

// ===========================================================================
// degree-bucket ordering: nodes grouped by exact degree -> uniform waves
// ===========================================================================
__global__ void dhist_kernel(const int* __restrict__ rowStart, int* __restrict__ dh, int N) {
    int i = blockIdx.x * blockDim.x + threadIdx.x;
    if (i >= N) return;
    int d = rowStart[i + 1] - rowStart[i];
    if (d > NDB - 1) d = NDB - 1;
    atomicAdd(&dh[d], 1);
}

__global__ void dscan_kernel(const int* __restrict__ dh, int* __restrict__ dcur) {
    if (threadIdx.x == 0) {
        int acc = 0;
        for (int b = 0; b < NDB; ++b) { dcur[b] = acc; acc += dh[b]; }
    }
}

__global__ void dorder_kernel(const int* __restrict__ rowStart, int* __restrict__ dcur,
                              int* __restrict__ node_order, int N) {
    int i = blockIdx.x * blockDim.x + threadIdx.x;
    if (i >= N) return;
    int d = rowStart[i + 1] - rowStart[i];
    if (d > NDB - 1) d = NDB - 1;
    int p = atomicAdd(&dcur[d], 1);
    node_order[p] = i;
}

// ===========================================================================
// eid scatter: only 4B edge ids scattered (48MB target -> L3-absorbed)
// ===========================================================================
__global__ void eid_scatter_kernel(const int* __restrict__ dst, int* __restrict__ cursor,
                                   int* __restrict__ eid_perm, int E) {
    long e = (long)blockIdx.x * blockDim.x + threadIdx.x;
    if (e >= E) return;
    int dd = dst[e];
    int pos = atomicAdd(&cursor[dd], 1);
    eid_perm[pos] = (int)e;
}

// gather-permute: coalesced writes, random reads of ea
__global__ void gperm_kernel(const int* __restrict__ eid_perm, const int* __restrict__ src,
                             const float* __restrict__ ea,
                             int* __restrict__ src_perm, float* __restrict__ ea_perm, int E) {
    long k = (long)blockIdx.x * blockDim.x + threadIdx.x;
    if (k >= E) return;
    int e = eid_perm[k];
    src_perm[k] = src[e];
    const float2* s = (const float2*)(ea + (size_t)e * HID);
    float2 a = s[0], b = s[1], c = s[2];
    float4* o = (float4*)(ea_perm + (size_t)k * HS);
    o[0] = make_float4(a.x, a.y, b.x, b.y);
    o[1] = make_float4(c.x, c.y, 0.f, 0.f);
}

// ===========================================================================
// fused GINE layer: degree-ordered node-gather + 6x6 update, no atomics
// ===========================================================================
__global__ void __launch_bounds__(256) layer_kernel(
        const float* __restrict__ h, const float* __restrict__ ea_perm,
        const int* __restrict__ src_perm, const int* __restrict__ rowStart,
        const int* __restrict__ node_order,
        const float* __restrict__ W, const float* __restrict__ b,
        float* __restrict__ out, int N, int do_relu) {
    __shared__ float sW[HID * HID];
    __shared__ float sb[HID];
    if (threadIdx.x < HID * HID) sW[threadIdx.x] = W[threadIdx.x];
    if (threadIdx.x < HID) sb[threadIdx.x] = b[threadIdx.x];
    __syncthreads();

    int gid = blockIdx.x * blockDim.x + threadIdx.x;
    if (gid >= N) return;
    int i = node_order[gid];
    int beg = rowStart[i], end = rowStart[i + 1];

    float4 h0 = *(const float4*)(h + (size_t)i * HS);
    float4 h1 = *(const float4*)(h + (size_t)i * HS + 4);
    float t0 = h0.x, t1 = h0.y, t2 = h0.z, t3 = h0.w, t4 = h1.x, t5 = h1.y;

    for (int k = beg; k < end; ++k) {
        int s = src_perm[k];
        float4 e0 = *(const float4*)(ea_perm + (size_t)k * HS);
        float4 e1 = *(const float4*)(ea_perm + (size_t)k * HS + 4);
        float4 g0 = *(const float4*)(h + (size_t)s * HS);
        float4 g1 = *(const float4*)(h + (size_t)s * HS + 4);
        t0 += fmaxf(g0.x + e0.x, 0.f);
        t1 += fmaxf(g0.y + e0.y, 0.f);
        t2 += fmaxf(g0.z + e0.z, 0.f);
        t3 += fmaxf(g0.w + e0.w, 0.f);
        t4 += fmaxf(g1.x + e1.x, 0.f);
        t5 += fmaxf(g1.y + e1.y, 0.f);
    }

    float o[HID];
#pragma unroll
    for (int d = 0; d < HID; ++d) o[d] = sb[d];
    float tv[HID] = {t0, t1, t2, t3, t4, t5};
#pragma unroll
    for (int k = 0; k < HID; ++k)
#pragma unroll
        for (int d = 0; d < HID; ++d) o[d] += tv[k] * sW[k * HID + d];
    if (do_relu)
#pragma unroll
        for (int d = 0; d < HID; ++d) o[d] = fmaxf(o[d], 0.f);

    float4* op = (float4*)(out + (size_t)i * HS);
    op[0] = make_float4(o[0], o[1], o[2], o[3]);
    op[1] = make_float4(o[4], o[5], 0.f, 0.f);
}

// ===========================================================================
// tier D fallback: atomic edge pass + node update (padded layouts)
// ===========================================================================
__global__ void edge_kernel(const float* __restrict__ h, const float* __restrict__ edge_attr,
                            const int* __restrict__ src, const int* __restrict__ dst,
                            float* __restrict__ agg, int E) {
    long e = (long)blockIdx.x * blockDim.x + threadIdx.x;
    if (e >= E) return;
    int s = src[e], d = dst[e];
    const float2* ea = (const float2*)(edge_attr + (size_t)e * HID);
    float4 g0 = *(const float4*)(h + (size_t)s * HS);
    float4 g1 = *(const float4*)(h + (size_t)s * HS + 4);
    float2 a0 = ea[0], a1 = ea[1], a2 = ea[2];
    float* ag = agg + (size_t)d * HID;
    atomicAdd(ag + 0, fmaxf(g0.x + a0.x, 0.f));
    atomicAdd(ag + 1, fmaxf(g0.y + a0.y, 0.f));
    atomicAdd(ag + 2, fmaxf(g0.z + a1.x, 0.f));
    atomicAdd(ag + 3, fmaxf(g0.w + a1.y, 0.f));
    atomicAdd(ag + 4, fmaxf(g1.x + a2.x, 0.f));
    atomicAdd(ag + 5, fmaxf(g1.y + a2.y, 0.f));
}

__global__ void node_kernel(const float* __restrict__ h, const float* __restrict__ agg,
                            const float* __restrict__ W, const float* __restrict__ b,
                            float* __restrict__ out, int N, int do_relu) {
    __shared__ float sW[HID * HID];
    __shared__ float sb[HID];
    if (threadIdx.x < HID * HID) sW[threadIdx.x] = W[threadIdx.x];
    if (threadIdx.x < HID) sb[threadIdx.x] = b[threadIdx.x];
    __syncthreads();
    int i = blockIdx.x * blockDim.x + threadIdx.x;
    if (i >= N) return;
    float4 h0 = *(const float4*)(h + (size_t)i * HS);
    float4 h1 = *(const float4*)(h + (size_t)i * HS + 4);
    const float2* ap = (const float2*)(agg + (size_t)i * HID);
    float2 g0 = ap[0], g1 = ap[1], g2 = ap[2];
    float tv[HID];
    tv[0] = h0.x + g0.x; tv[1] = h0.y + g0.y;
    tv[2] = h0.z + g1.x; tv[3] = h0.w + g1.y;
    tv[4] = h1.x + g2.x; tv[5] = h1.y + g2.y;
    float o[HID];
#pragma unroll
    for (int d = 0; d < HID; ++d) o[d] = sb[d];
#pragma unroll
    for (int k = 0; k < HID; ++k)
#pragma unroll
        for (int d = 0; d < HID; ++d) o[d] += tv[k] * sW[k * HID + d];
    if (do_relu)
#pragma unroll
        for (int d = 0; d < HID; ++d) o[d] = fmaxf(o[d], 0.f);
    float4* op = (float4*)(out + (size_t)i * HS);
    op[0] = make_float4(o[0], o[1], o[2], o[3]);
    op[1] = make_float4(o[4], o[5], 0.f, 0.f);
}

// ===========================================================================
// pool + output (padded h)
// ===========================================================================
__global__ void pool_kernel(const float* __restrict__ h, const int* __restrict__ batch,
                            float* __restrict__ sums, float* __restrict__ cnts, int N) {
    int i = blockIdx.x * blockDim.x + threadIdx.x;
    int lane = threadIdx.x & 63;
    bool active = (i < N);
    float v[HID];
    int g = -1;
    if (active) {
        g = batch[i];
        float4 h0 = *(const float4*)(h + (size_t)i * HS);
        float4 h1 = *(const float4*)(h + (size_t)i * HS + 4);
        v[0] = h0.x; v[1] = h0.y; v[2] = h0.z; v[3] = h0.w; v[4] = h1.x; v[5] = h1.y;
    } else {
#pragma unroll
        for (int d = 0; d < HID; ++d) v[d] = 0.0f;
    }
    int g0 = __shfl(g, 0);
    bool uniform = __all(active) && __all(g == g0);
    if (uniform) {
#pragma unroll
        for (int d = 0; d < HID; ++d) {
            float s = v[d];
            for (int off = 32; off > 0; off >>= 1) s += __shfl_down(s, off);
            if (lane == 0) atomicAdd(&sums[(size_t)g0 * HID + d], s);
        }
        if (lane == 0) atomicAdd(&cnts[g0], 64.0f);
    } else if (active) {
#pragma unroll
        for (int d = 0; d < HID; ++d) atomicAdd(&sums[(size_t)g * HID + d], v[d]);
        atomicAdd(&cnts[g], 1.0f);
    }
}

__global__ void out_kernel(const float* __restrict__ sums, const float* __restrict__ cnts,
                           const float* __restrict__ Wl, const float* __restrict__ bl,
                           float* __restrict__ out) {
    int gI = blockIdx.x * blockDim.x + threadIdx.x;
    if (gI >= NUM_GRAPHS) return;
    float c = fmaxf(cnts[gI], 1.0f);
    float acc = bl[0];
#pragma unroll
    for (int d = 0; d < HID; ++d) acc += (sums[(size_t)gI * HID + d] / c) * Wl[d];
    out[gI] = acc;
}

// ===========================================================================
extern "C" void kernel_launch(void* const* d_in, const int* in_sizes, int n_in,
                              void* d_out, int out_size, void* d_ws, size_t ws_size,
                              hipStream_t stream) {
    const float* x         = (const float*)d_in[0];
    const int*   eidx      = (const int*)d_in[1];
    const float* edge_attr = (const float*)d_in[2];
    const int*   batch     = (const int*)d_in[3];
    const float* W1 = (const float*)d_in[4];
    const float* b1 = (const float*)d_in[5];
    const float* W2 = (const float*)d_in[6];
    const float* b2 = (const float*)d_in[7];
    const float* W3 = (const float*)d_in[8];
    const float* b3 = (const float*)d_in[9];
    const float* Wl = (const float*)d_in[10];
    const float* bl = (const float*)d_in[11];

    const int N = in_sizes[0] / HID;
    const int E = in_sizes[1] / 2;
    const int* src = eidx;
    const int* dst = eidx + E;

    const int TB = 256;
    const int nbl = (N + TB - 1) / TB;
    const int ebl = (E + TB - 1) / TB;
    const int hbl = ((E + 3) / 4 + TB - 1) / TB;
    const int scanBlocks = (N + SCAN_B - 1) / SCAN_B;
    const bool canScan = (scanBlocks <= SCAN_B);

    char* w = (char*)d_ws;
    size_t off = 0;
    auto alloc = [&](size_t bytes) { void* p = w + off; off += (bytes + 255) & ~(size_t)255; return p; };

    float* hX       = (float*)alloc((size_t)N * HS * sizeof(float));   // 32MB
    float* hA       = (float*)alloc((size_t)N * HS * sizeof(float));   // 32MB
    float* hB       = (float*)alloc((size_t)N * HS * sizeof(float));   // 32MB
    float* sums     = (float*)alloc((size_t)NUM_GRAPHS * HID * sizeof(float));
    float* cnts     = (float*)alloc((size_t)NUM_GRAPHS * sizeof(float));
    size_t tierDneed = off + (size_t)N * HID * sizeof(float);          // + agg

    float* ea_perm  = (float*)alloc((size_t)E * HS * sizeof(float));   // 384MB
    int*   src_perm = (int*)alloc((size_t)E * sizeof(int));            // 48MB
    int*   eid_perm = (int*)alloc((size_t)E * sizeof(int));            // 48MB
    int*   deg      = (int*)alloc((size_t)N * sizeof(int));
    int*   rowStart = (int*)alloc((size_t)(N + 2) * sizeof(int));
    int*   cursor   = (int*)alloc((size_t)N * sizeof(int));
    int*   node_order = (int*)alloc((size_t)N * sizeof(int));
    int*   blockSums  = (int*)alloc((size_t)SCAN_B * sizeof(int));
    int*   dh         = (int*)alloc((size_t)NDB * sizeof(int));
    int*   dcur       = (int*)alloc((size_t)NDB * sizeof(int));
    size_t tierAneed  = off;

    pad_kernel<<<nbl, TB, 0, stream>>>(x, hX, N);

    if (canScan && ws_size >= tierAneed) {
        // ---- CSR build ----
        hipMemsetAsync(deg, 0, (size_t)N * sizeof(int), stream);
        hipMemsetAsync(blockSums, 0, (size_t)SCAN_B * sizeof(int), stream);
        hipMemsetAsync(dh, 0, (size_t)NDB * sizeof(int), stream);
        hist_kernel<<<hbl, TB, 0, stream>>>(dst, deg, E);
        scan_block_kernel<<<scanBlocks, SCAN_B, 0, stream>>>(deg, blockSums, N);
        scan_block_kernel<<<1, SCAN_B, 0, stream>>>(blockSums, nullptr, scanBlocks);
        scan_finish_kernel<<<nbl, TB, 0, stream>>>(deg, blockSums, rowStart, cursor, N, E);

        // ---- degree-uniform node ordering ----
        dhist_kernel<<<nbl, TB, 0, stream>>>(rowStart, dh, N);
        dscan_kernel<<<1, 64, 0, stream>>>(dh, dcur);
        dorder_kernel<<<nbl, TB, 0, stream>>>(rowStart, dcur, node_order, N);

        // ---- eid scatter (4B, L3-absorbed) + gather-permute (coalesced writes) ----
        eid_scatter_kernel<<<ebl, TB, 0, stream>>>(dst, cursor, eid_perm, E);
        gperm_kernel<<<ebl, TB, 0, stream>>>(eid_perm, src, edge_attr, src_perm, ea_perm, E);

        // ---- layers ----
        layer_kernel<<<nbl, TB, 0, stream>>>(hX, ea_perm, src_perm, rowStart, node_order, W1, b1, hA, N, 1);
        layer_kernel<<<nbl, TB, 0, stream>>>(hA, ea_perm, src_perm, rowStart, node_order, W2, b2, hB, N, 1);
        layer_kernel<<<nbl, TB, 0, stream>>>(hB, ea_perm, src_perm, rowStart, node_order, W3, b3, hA, N, 0);
    } else {
        // ---- tier D: atomic fallback ----
        float* agg = (float*)((char*)w + tierDneed - (size_t)N * HID * sizeof(float));
        const size_t szAgg = (size_t)N * HID * sizeof(float);
        hipMemsetAsync(agg, 0, szAgg, stream);
        edge_kernel<<<ebl, TB, 0, stream>>>(hX, edge_attr, src, dst, agg, E);
        node_kernel<<<nbl, TB, 0, stream>>>(hX, agg, W1, b1, hA, N, 1);
        hipMemsetAsync(agg, 0, szAgg, stream);
        edge_kernel<<<ebl, TB, 0, stream>>>(hA, edge_attr, src, dst, agg, E);
        node_kernel<<<nbl, TB, 0, stream>>>(hA, agg, W2, b2, hB, N, 1);
        hipMemsetAsync(agg, 0, szAgg, stream);
        edge_kernel<<<ebl, TB, 0, stream>>>(hB, edge_attr, src, dst, agg, E);
        node_kernel<<<nbl, TB, 0, stream>>>(hB, agg, W3, b3, hA, N, 0);
    }

    hipMemsetAsync(sums, 0, (size_t)NUM_GRAPHS * HID * sizeof(float), stream);
    hipMemsetAsync(cnts, 0, (size_t)NUM_GRAPHS * sizeof(float), stream);
    pool_kernel<<<nbl, TB, 0, stream>>>(hA, batch, sums, cnts, N);
    out_kernel<<<(NUM_GRAPHS + TB - 1) / TB, TB, 0, stream>>>(sums, cnts, Wl, bl, (float*)d_out);
}

// Round 5
// 2633.115 us; speedup vs baseline: 4.0027x; 4.0027x over previous
//
#include <hip/hip_runtime.h>

#define HID 6
#define HS  8                   // padded row stride (floats) for h buffers
#define EAS 6                   // packed row stride for ea_perm
#define NUM_GRAPHS 1000
#define SCAN_B 1024

// ===========================================================================
// pad x (N x 6) -> hX (N x 8)
// ===========================================================================
__global__ void pad_kernel(const float* __restrict__ x, float* __restrict__ hX, int N) {
    int i = blockIdx.x * blockDim.x + threadIdx.x;
    if (i >= N) return;
    const float2* s = (const float2*)(x + (size_t)i * HID);
    float2 a = s[0], b = s[1], c = s[2];
    float4* o = (float4*)(hX + (size_t)i * HS);
    o[0] = make_float4(a.x, a.y, b.x, b.y);
    o[1] = make_float4(c.x, c.y, 0.f, 0.f);
}

// ===========================================================================
// degree histogram (atomics into 1M-entry array: low contention)
// ===========================================================================
__global__ void hist_kernel(const int* __restrict__ dst, int* __restrict__ deg, int E) {
    long i = ((long)blockIdx.x * blockDim.x + threadIdx.x) * 4;
    if (i + 4 <= E) {
        int4 v = *(const int4*)(dst + i);
        atomicAdd(&deg[v.x], 1);
        atomicAdd(&deg[v.y], 1);
        atomicAdd(&deg[v.z], 1);
        atomicAdd(&deg[v.w], 1);
    } else {
        for (long e = i; e < E; ++e) atomicAdd(&deg[dst[e]], 1);
    }
}

// in-place exclusive scan within 1024-blocks
__global__ void scan_block_kernel(int* __restrict__ data, int* __restrict__ blockSums, int N) {
    __shared__ int tmp[SCAN_B];
    int t = threadIdx.x;
    int i = blockIdx.x * SCAN_B + t;
    int v = (i < N) ? data[i] : 0;
    tmp[t] = v;
    __syncthreads();
    for (int off = 1; off < SCAN_B; off <<= 1) {
        int a = (t >= off) ? tmp[t - off] : 0;
        __syncthreads();
        tmp[t] += a;
        __syncthreads();
    }
    if (i < N) data[i] = tmp[t] - v;
    if (blockSums && t == SCAN_B - 1) blockSums[blockIdx.x] = tmp[SCAN_B - 1];
}

__global__ void scan_finish_kernel(const int* __restrict__ scanned,
                                   const int* __restrict__ blockOffsets,
                                   int* __restrict__ rowStart, int* __restrict__ cursor,
                                   int N, int E) {
    int i = blockIdx.x * blockDim.x + threadIdx.x;
    if (i < N) {
        int v = scanned[i] + blockOffsets[i >> 10];
        rowStart[i] = v;
        cursor[i] = v;
    }
    if (i == 0) rowStart[N] = E;
}

// ===========================================================================
// scatter only 4B ids: eid + src (both L3-absorbed), 1 cursor atomic per edge
// ===========================================================================
__global__ void eid_scatter_kernel(const int* __restrict__ src, const int* __restrict__ dst,
                                   int* __restrict__ cursor,
                                   int* __restrict__ eid_perm, int* __restrict__ src_perm, int E) {
    long e = (long)blockIdx.x * blockDim.x + threadIdx.x;
    if (e >= E) return;
    int dd = dst[e];
    int pos = atomicAdd(&cursor[dd], 1);
    eid_perm[pos] = (int)e;
    src_perm[pos] = src[e];
}

// gather-permute ea: streamed eid_perm read, random ea read, coalesced write
__global__ void gperm_kernel(const int* __restrict__ eid_perm,
                             const float* __restrict__ ea,
                             float* __restrict__ ea_perm, int E) {
    long k = (long)blockIdx.x * blockDim.x + threadIdx.x;
    if (k >= E) return;
    int e = eid_perm[k];
    const float2* s = (const float2*)(ea + (size_t)e * HID);
    float2 a = s[0], b = s[1], c = s[2];
    float2* o = (float2*)(ea_perm + (size_t)k * EAS);
    o[0] = a; o[1] = b; o[2] = c;
}

// ===========================================================================
// fused GINE layer: 4 lanes per node; shuffle-reduce; lane0 does 6x6 update
// ===========================================================================
__global__ void __launch_bounds__(256) layer_kernel(
        const float* __restrict__ h, const float* __restrict__ ea_perm,
        const int* __restrict__ src_perm, const int* __restrict__ rowStart,
        const float* __restrict__ W, const float* __restrict__ b,
        float* __restrict__ out, int N, int do_relu) {
    __shared__ float sW[HID * HID];
    __shared__ float sb[HID];
    if (threadIdx.x < HID * HID) sW[threadIdx.x] = W[threadIdx.x];
    if (threadIdx.x < HID) sb[threadIdx.x] = b[threadIdx.x];
    __syncthreads();

    int t = threadIdx.x;
    int j = t & 3;                               // lane within node group
    int i = blockIdx.x * 64 + (t >> 2);          // node index
    if (i >= N) return;

    int beg = rowStart[i], end = rowStart[i + 1];

    float t0 = 0.f, t1 = 0.f, t2 = 0.f, t3 = 0.f, t4 = 0.f, t5 = 0.f;
    for (int k = beg + j; k < end; k += 4) {
        int s = src_perm[k];
        const float2* ap = (const float2*)(ea_perm + (size_t)k * EAS);
        float2 e0 = ap[0], e1 = ap[1], e2 = ap[2];
        float4 g0 = *(const float4*)(h + (size_t)s * HS);
        float4 g1 = *(const float4*)(h + (size_t)s * HS + 4);
        t0 += fmaxf(g0.x + e0.x, 0.f);
        t1 += fmaxf(g0.y + e0.y, 0.f);
        t2 += fmaxf(g0.z + e1.x, 0.f);
        t3 += fmaxf(g0.w + e1.y, 0.f);
        t4 += fmaxf(g1.x + e2.x, 0.f);
        t5 += fmaxf(g1.y + e2.y, 0.f);
    }

    // reduce across the 4 lanes of this node group
    t0 += __shfl_xor(t0, 1); t1 += __shfl_xor(t1, 1); t2 += __shfl_xor(t2, 1);
    t3 += __shfl_xor(t3, 1); t4 += __shfl_xor(t4, 1); t5 += __shfl_xor(t5, 1);
    t0 += __shfl_xor(t0, 2); t1 += __shfl_xor(t1, 2); t2 += __shfl_xor(t2, 2);
    t3 += __shfl_xor(t3, 2); t4 += __shfl_xor(t4, 2); t5 += __shfl_xor(t5, 2);

    if (j != 0) return;

    float4 h0 = *(const float4*)(h + (size_t)i * HS);
    float4 h1 = *(const float4*)(h + (size_t)i * HS + 4);
    float tv[HID];
    tv[0] = t0 + h0.x; tv[1] = t1 + h0.y; tv[2] = t2 + h0.z;
    tv[3] = t3 + h0.w; tv[4] = t4 + h1.x; tv[5] = t5 + h1.y;

    float o[HID];
#pragma unroll
    for (int d = 0; d < HID; ++d) o[d] = sb[d];
#pragma unroll
    for (int k = 0; k < HID; ++k)
#pragma unroll
        for (int d = 0; d < HID; ++d) o[d] += tv[k] * sW[k * HID + d];
    if (do_relu)
#pragma unroll
        for (int d = 0; d < HID; ++d) o[d] = fmaxf(o[d], 0.f);

    float4* op = (float4*)(out + (size_t)i * HS);
    op[0] = make_float4(o[0], o[1], o[2], o[3]);
    op[1] = make_float4(o[4], o[5], 0.f, 0.f);
}

// ===========================================================================
// tier D fallback: atomic edge pass + node update (padded layouts)
// ===========================================================================
__global__ void edge_kernel(const float* __restrict__ h, const float* __restrict__ edge_attr,
                            const int* __restrict__ src, const int* __restrict__ dst,
                            float* __restrict__ agg, int E) {
    long e = (long)blockIdx.x * blockDim.x + threadIdx.x;
    if (e >= E) return;
    int s = src[e], d = dst[e];
    const float2* ea = (const float2*)(edge_attr + (size_t)e * HID);
    float4 g0 = *(const float4*)(h + (size_t)s * HS);
    float4 g1 = *(const float4*)(h + (size_t)s * HS + 4);
    float2 a0 = ea[0], a1 = ea[1], a2 = ea[2];
    float* ag = agg + (size_t)d * HID;
    atomicAdd(ag + 0, fmaxf(g0.x + a0.x, 0.f));
    atomicAdd(ag + 1, fmaxf(g0.y + a0.y, 0.f));
    atomicAdd(ag + 2, fmaxf(g0.z + a1.x, 0.f));
    atomicAdd(ag + 3, fmaxf(g0.w + a1.y, 0.f));
    atomicAdd(ag + 4, fmaxf(g1.x + a2.x, 0.f));
    atomicAdd(ag + 5, fmaxf(g1.y + a2.y, 0.f));
}

__global__ void node_kernel(const float* __restrict__ h, const float* __restrict__ agg,
                            const float* __restrict__ W, const float* __restrict__ b,
                            float* __restrict__ out, int N, int do_relu) {
    __shared__ float sW[HID * HID];
    __shared__ float sb[HID];
    if (threadIdx.x < HID * HID) sW[threadIdx.x] = W[threadIdx.x];
    if (threadIdx.x < HID) sb[threadIdx.x] = b[threadIdx.x];
    __syncthreads();
    int i = blockIdx.x * blockDim.x + threadIdx.x;
    if (i >= N) return;
    float4 h0 = *(const float4*)(h + (size_t)i * HS);
    float4 h1 = *(const float4*)(h + (size_t)i * HS + 4);
    const float2* ap = (const float2*)(agg + (size_t)i * HID);
    float2 g0 = ap[0], g1 = ap[1], g2 = ap[2];
    float tv[HID];
    tv[0] = h0.x + g0.x; tv[1] = h0.y + g0.y;
    tv[2] = h0.z + g1.x; tv[3] = h0.w + g1.y;
    tv[4] = h1.x + g2.x; tv[5] = h1.y + g2.y;
    float o[HID];
#pragma unroll
    for (int d = 0; d < HID; ++d) o[d] = sb[d];
#pragma unroll
    for (int k = 0; k < HID; ++k)
#pragma unroll
        for (int d = 0; d < HID; ++d) o[d] += tv[k] * sW[k * HID + d];
    if (do_relu)
#pragma unroll
        for (int d = 0; d < HID; ++d) o[d] = fmaxf(o[d], 0.f);
    float4* op = (float4*)(out + (size_t)i * HS);
    op[0] = make_float4(o[0], o[1], o[2], o[3]);
    op[1] = make_float4(o[4], o[5], 0.f, 0.f);
}

// ===========================================================================
// pool + output (padded h)
// ===========================================================================
__global__ void pool_kernel(const float* __restrict__ h, const int* __restrict__ batch,
                            float* __restrict__ sums, float* __restrict__ cnts, int N) {
    int i = blockIdx.x * blockDim.x + threadIdx.x;
    int lane = threadIdx.x & 63;
    bool active = (i < N);
    float v[HID];
    int g = -1;
    if (active) {
        g = batch[i];
        float4 h0 = *(const float4*)(h + (size_t)i * HS);
        float4 h1 = *(const float4*)(h + (size_t)i * HS + 4);
        v[0] = h0.x; v[1] = h0.y; v[2] = h0.z; v[3] = h0.w; v[4] = h1.x; v[5] = h1.y;
    } else {
#pragma unroll
        for (int d = 0; d < HID; ++d) v[d] = 0.0f;
    }
    int g0 = __shfl(g, 0);
    bool uniform = __all(active) && __all(g == g0);
    if (uniform) {
#pragma unroll
        for (int d = 0; d < HID; ++d) {
            float s = v[d];
            for (int off = 32; off > 0; off >>= 1) s += __shfl_down(s, off);
            if (lane == 0) atomicAdd(&sums[(size_t)g0 * HID + d], s);
        }
        if (lane == 0) atomicAdd(&cnts[g0], 64.0f);
    } else if (active) {
#pragma unroll
        for (int d = 0; d < HID; ++d) atomicAdd(&sums[(size_t)g * HID + d], v[d]);
        atomicAdd(&cnts[g], 1.0f);
    }
}

__global__ void out_kernel(const float* __restrict__ sums, const float* __restrict__ cnts,
                           const float* __restrict__ Wl, const float* __restrict__ bl,
                           float* __restrict__ out) {
    int gI = blockIdx.x * blockDim.x + threadIdx.x;
    if (gI >= NUM_GRAPHS) return;
    float c = fmaxf(cnts[gI], 1.0f);
    float acc = bl[0];
#pragma unroll
    for (int d = 0; d < HID; ++d) acc += (sums[(size_t)gI * HID + d] / c) * Wl[d];
    out[gI] = acc;
}

// ===========================================================================
extern "C" void kernel_launch(void* const* d_in, const int* in_sizes, int n_in,
                              void* d_out, int out_size, void* d_ws, size_t ws_size,
                              hipStream_t stream) {
    const float* x         = (const float*)d_in[0];
    const int*   eidx      = (const int*)d_in[1];
    const float* edge_attr = (const float*)d_in[2];
    const int*   batch     = (const int*)d_in[3];
    const float* W1 = (const float*)d_in[4];
    const float* b1 = (const float*)d_in[5];
    const float* W2 = (const float*)d_in[6];
    const float* b2 = (const float*)d_in[7];
    const float* W3 = (const float*)d_in[8];
    const float* b3 = (const float*)d_in[9];
    const float* Wl = (const float*)d_in[10];
    const float* bl = (const float*)d_in[11];

    const int N = in_sizes[0] / HID;
    const int E = in_sizes[1] / 2;
    const int* src = eidx;
    const int* dst = eidx + E;

    const int TB = 256;
    const int nbl = (N + TB - 1) / TB;
    const int ebl = (E + TB - 1) / TB;
    const int hbl = ((E + 3) / 4 + TB - 1) / TB;
    const int lbl = (N + 63) / 64;              // layer_kernel: 64 nodes/block
    const int scanBlocks = (N + SCAN_B - 1) / SCAN_B;
    const bool canScan = (scanBlocks <= SCAN_B);

    char* w = (char*)d_ws;
    size_t off = 0;
    auto alloc = [&](size_t bytes) { void* p = w + off; off += (bytes + 255) & ~(size_t)255; return p; };

    float* hX       = (float*)alloc((size_t)N * HS * sizeof(float));   // 32MB
    float* hA       = (float*)alloc((size_t)N * HS * sizeof(float));   // 32MB
    float* hB       = (float*)alloc((size_t)N * HS * sizeof(float));   // 32MB
    float* sums     = (float*)alloc((size_t)NUM_GRAPHS * HID * sizeof(float));
    float* cnts     = (float*)alloc((size_t)NUM_GRAPHS * sizeof(float));
    size_t tierDneed = off + (size_t)N * HID * sizeof(float);          // + agg

    float* ea_perm  = (float*)alloc((size_t)E * EAS * sizeof(float));  // 288MB
    int*   src_perm = (int*)alloc((size_t)E * sizeof(int));            // 48MB
    int*   eid_perm = (int*)alloc((size_t)E * sizeof(int));            // 48MB
    int*   deg      = (int*)alloc((size_t)N * sizeof(int));
    int*   rowStart = (int*)alloc((size_t)(N + 2) * sizeof(int));
    int*   cursor   = (int*)alloc((size_t)N * sizeof(int));
    int*   blockSums= (int*)alloc((size_t)SCAN_B * sizeof(int));
    size_t tierAneed = off;

    pad_kernel<<<nbl, TB, 0, stream>>>(x, hX, N);

    if (canScan && ws_size >= tierAneed) {
        // ---- CSR build ----
        hipMemsetAsync(deg, 0, (size_t)N * sizeof(int), stream);
        hipMemsetAsync(blockSums, 0, (size_t)SCAN_B * sizeof(int), stream);
        hist_kernel<<<hbl, TB, 0, stream>>>(dst, deg, E);
        scan_block_kernel<<<scanBlocks, SCAN_B, 0, stream>>>(deg, blockSums, N);
        scan_block_kernel<<<1, SCAN_B, 0, stream>>>(blockSums, nullptr, scanBlocks);
        scan_finish_kernel<<<nbl, TB, 0, stream>>>(deg, blockSums, rowStart, cursor, N, E);

        // ---- 4B id scatter + gather-permute ----
        eid_scatter_kernel<<<ebl, TB, 0, stream>>>(src, dst, cursor, eid_perm, src_perm, E);
        gperm_kernel<<<ebl, TB, 0, stream>>>(eid_perm, edge_attr, ea_perm, E);

        // ---- layers (4 lanes per node) ----
        layer_kernel<<<lbl, TB, 0, stream>>>(hX, ea_perm, src_perm, rowStart, W1, b1, hA, N, 1);
        layer_kernel<<<lbl, TB, 0, stream>>>(hA, ea_perm, src_perm, rowStart, W2, b2, hB, N, 1);
        layer_kernel<<<lbl, TB, 0, stream>>>(hB, ea_perm, src_perm, rowStart, W3, b3, hA, N, 0);
    } else {
        // ---- tier D: atomic fallback ----
        float* agg = (float*)((char*)w + tierDneed - (size_t)N * HID * sizeof(float));
        const size_t szAgg = (size_t)N * HID * sizeof(float);
        hipMemsetAsync(agg, 0, szAgg, stream);
        edge_kernel<<<ebl, TB, 0, stream>>>(hX, edge_attr, src, dst, agg, E);
        node_kernel<<<nbl, TB, 0, stream>>>(hX, agg, W1, b1, hA, N, 1);
        hipMemsetAsync(agg, 0, szAgg, stream);
        edge_kernel<<<ebl, TB, 0, stream>>>(hA, edge_attr, src, dst, agg, E);
        node_kernel<<<nbl, TB, 0, stream>>>(hA, agg, W2, b2, hB, N, 1);
        hipMemsetAsync(agg, 0, szAgg, stream);
        edge_kernel<<<ebl, TB, 0, stream>>>(hB, edge_attr, src, dst, agg, E);
        node_kernel<<<nbl, TB, 0, stream>>>(hB, agg, W3, b3, hA, N, 0);
    }

    hipMemsetAsync(sums, 0, (size_t)NUM_GRAPHS * HID * sizeof(float), stream);
    hipMemsetAsync(cnts, 0, (size_t)NUM_GRAPHS * sizeof(float), stream);
    pool_kernel<<<nbl, TB, 0, stream>>>(hA, batch, sums, cnts, N);
    out_kernel<<<(NUM_GRAPHS + TB - 1) / TB, TB, 0, stream>>>(sums, cnts, Wl, bl, (float*)d_out);
}

// Round 6
// 1873.844 us; speedup vs baseline: 5.6245x; 1.4052x over previous
//
#include <hip/hip_runtime.h>

#define HID 6
#define HS  8                   // padded row stride (floats) for h buffers
#define NUM_GRAPHS 1000
#define BSHIFT 11
#define BNODES (1 << BSHIFT)    // 2048 nodes per bucket
#define MAXNB 512               // max buckets supported by pass1 LDS
#define P1_CHUNK 4096
#define P1_PERT  16             // P1_CHUNK / 256

// ===========================================================================
// pad x (N x 6) -> hX (N x 8)
// ===========================================================================
__global__ void pad_kernel(const float* __restrict__ x, float* __restrict__ hX, int N) {
    int i = blockIdx.x * blockDim.x + threadIdx.x;
    if (i >= N) return;
    const float2* s = (const float2*)(x + (size_t)i * HID);
    float2 a = s[0], b = s[1], c = s[2];
    float4* o = (float4*)(hX + (size_t)i * HS);
    o[0] = make_float4(a.x, a.y, b.x, b.y);
    o[1] = make_float4(c.x, c.y, 0.f, 0.f);
}

__global__ void init_gcursor_kernel(int* __restrict__ gcursor, int NB, int cap) {
    int b = blockIdx.x * blockDim.x + threadIdx.x;
    if (b < NB) gcursor[b] = b * cap;
}

// ===========================================================================
// pass1: bin edges by dst>>BSHIFT into fixed-capacity bucket regions.
// Per block: LDS hist -> one global atomic per touched bucket -> LDS-cursor
// scatter of {src, dloc(ushort), ea 24B}. No per-edge global atomics.
// ===========================================================================
__global__ void __launch_bounds__(256) pass1_kernel(
        const int* __restrict__ src, const int* __restrict__ dst,
        const float* __restrict__ ea,
        int* __restrict__ gcursor,
        int* __restrict__ src_perm, unsigned short* __restrict__ dloc_perm,
        float* __restrict__ ea_perm,
        int E, int cap, int NB) {
    __shared__ int hist[MAXNB];
    __shared__ int base[MAXNB];
    int t = threadIdx.x;
    long e0 = (long)blockIdx.x * P1_CHUNK;

    for (int b = t; b < MAXNB; b += 256) hist[b] = 0;
    __syncthreads();

    int d[P1_PERT];
#pragma unroll
    for (int j = 0; j < P1_PERT; ++j) {
        long e = e0 + t + (long)j * 256;
        d[j] = (e < E) ? dst[e] : -1;
        if (d[j] >= 0) atomicAdd(&hist[d[j] >> BSHIFT], 1);
    }
    __syncthreads();

    for (int b = t; b < NB; b += 256) {
        int c = hist[b];
        base[b] = c ? atomicAdd(&gcursor[b], c) : 0;
    }
    __syncthreads();
    for (int b = t; b < MAXNB; b += 256) hist[b] = 0;
    __syncthreads();

#pragma unroll
    for (int j = 0; j < P1_PERT; ++j) {
        long e = e0 + t + (long)j * 256;
        if (e >= E) continue;
        int b = d[j] >> BSHIFT;
        int pos = base[b] + atomicAdd(&hist[b], 1);
        src_perm[pos] = src[e];
        dloc_perm[pos] = (unsigned short)(d[j] & (BNODES - 1));
        const float2* s = (const float2*)(ea + (size_t)e * HID);
        float2 a0 = s[0], a1 = s[1], a2 = s[2];
        float2* o = (float2*)(ea_perm + (size_t)pos * HID);
        o[0] = a0; o[1] = a1; o[2] = a2;
    }
}

// ===========================================================================
// bucket-fused GINE layer: one WG per bucket; LDS agg for 2048 nodes;
// stream bucket edges, LDS atomicAdd; epilogue = (h+agg)@W+b coalesced.
// ===========================================================================
__global__ void __launch_bounds__(256) layer_kernel(
        const float* __restrict__ h,
        const float* __restrict__ ea_perm,
        const int* __restrict__ src_perm,
        const unsigned short* __restrict__ dloc_perm,
        const int* __restrict__ gcursor,
        const float* __restrict__ W, const float* __restrict__ b,
        float* __restrict__ out, int N, int cap, int do_relu) {
    __shared__ float sagg[BNODES * HID];     // 48 KB
    __shared__ float sW[HID * HID];
    __shared__ float sb[HID];
    int t = threadIdx.x;
    int bk = blockIdx.x;
    if (t < HID * HID) sW[t] = W[t];
    if (t < HID) sb[t] = b[t];
    for (int i = t; i < BNODES * HID; i += 256) sagg[i] = 0.f;
    __syncthreads();

    long kbeg = (long)bk * cap;
    int cnt = gcursor[bk] - (int)((long)bk * cap);

    for (int k = t; k < cnt; k += 256) {
        long kk = kbeg + k;
        int s = src_perm[kk];
        int dl = dloc_perm[kk];
        const float2* ap = (const float2*)(ea_perm + (size_t)kk * HID);
        float2 e0 = ap[0], e1 = ap[1], e2 = ap[2];
        float4 g0 = *(const float4*)(h + (size_t)s * HS);
        float4 g1 = *(const float4*)(h + (size_t)s * HS + 4);
        float* p = sagg + (size_t)dl * HID;
        atomicAdd(p + 0, fmaxf(g0.x + e0.x, 0.f));
        atomicAdd(p + 1, fmaxf(g0.y + e0.y, 0.f));
        atomicAdd(p + 2, fmaxf(g0.z + e1.x, 0.f));
        atomicAdd(p + 3, fmaxf(g0.w + e1.y, 0.f));
        atomicAdd(p + 4, fmaxf(g1.x + e2.x, 0.f));
        atomicAdd(p + 5, fmaxf(g1.y + e2.y, 0.f));
    }
    __syncthreads();

    int nodeBase = bk << BSHIFT;
    for (int n = t; n < BNODES; n += 256) {
        int i = nodeBase + n;
        if (i >= N) break;
        float4 h0 = *(const float4*)(h + (size_t)i * HS);
        float4 h1 = *(const float4*)(h + (size_t)i * HS + 4);
        const float* sp = sagg + (size_t)n * HID;
        float tv[HID];
        tv[0] = h0.x + sp[0]; tv[1] = h0.y + sp[1]; tv[2] = h0.z + sp[2];
        tv[3] = h0.w + sp[3]; tv[4] = h1.x + sp[4]; tv[5] = h1.y + sp[5];
        float o[HID];
#pragma unroll
        for (int dd = 0; dd < HID; ++dd) o[dd] = sb[dd];
#pragma unroll
        for (int k = 0; k < HID; ++k)
#pragma unroll
            for (int dd = 0; dd < HID; ++dd) o[dd] += tv[k] * sW[k * HID + dd];
        if (do_relu)
#pragma unroll
            for (int dd = 0; dd < HID; ++dd) o[dd] = fmaxf(o[dd], 0.f);
        float4* op = (float4*)(out + (size_t)i * HS);
        op[0] = make_float4(o[0], o[1], o[2], o[3]);
        op[1] = make_float4(o[4], o[5], 0.f, 0.f);
    }
}

// ===========================================================================
// tier D fallback: atomic edge pass + node update (padded layouts)
// ===========================================================================
__global__ void edge_kernel(const float* __restrict__ h, const float* __restrict__ edge_attr,
                            const int* __restrict__ src, const int* __restrict__ dst,
                            float* __restrict__ agg, int E) {
    long e = (long)blockIdx.x * blockDim.x + threadIdx.x;
    if (e >= E) return;
    int s = src[e], d = dst[e];
    const float2* ea = (const float2*)(edge_attr + (size_t)e * HID);
    float4 g0 = *(const float4*)(h + (size_t)s * HS);
    float4 g1 = *(const float4*)(h + (size_t)s * HS + 4);
    float2 a0 = ea[0], a1 = ea[1], a2 = ea[2];
    float* ag = agg + (size_t)d * HID;
    atomicAdd(ag + 0, fmaxf(g0.x + a0.x, 0.f));
    atomicAdd(ag + 1, fmaxf(g0.y + a0.y, 0.f));
    atomicAdd(ag + 2, fmaxf(g0.z + a1.x, 0.f));
    atomicAdd(ag + 3, fmaxf(g0.w + a1.y, 0.f));
    atomicAdd(ag + 4, fmaxf(g1.x + a2.x, 0.f));
    atomicAdd(ag + 5, fmaxf(g1.y + a2.y, 0.f));
}

__global__ void node_kernel(const float* __restrict__ h, const float* __restrict__ agg,
                            const float* __restrict__ W, const float* __restrict__ b,
                            float* __restrict__ out, int N, int do_relu) {
    __shared__ float sW[HID * HID];
    __shared__ float sb[HID];
    if (threadIdx.x < HID * HID) sW[threadIdx.x] = W[threadIdx.x];
    if (threadIdx.x < HID) sb[threadIdx.x] = b[threadIdx.x];
    __syncthreads();
    int i = blockIdx.x * blockDim.x + threadIdx.x;
    if (i >= N) return;
    float4 h0 = *(const float4*)(h + (size_t)i * HS);
    float4 h1 = *(const float4*)(h + (size_t)i * HS + 4);
    const float2* ap = (const float2*)(agg + (size_t)i * HID);
    float2 g0 = ap[0], g1 = ap[1], g2 = ap[2];
    float tv[HID];
    tv[0] = h0.x + g0.x; tv[1] = h0.y + g0.y;
    tv[2] = h0.z + g1.x; tv[3] = h0.w + g1.y;
    tv[4] = h1.x + g2.x; tv[5] = h1.y + g2.y;
    float o[HID];
#pragma unroll
    for (int d = 0; d < HID; ++d) o[d] = sb[d];
#pragma unroll
    for (int k = 0; k < HID; ++k)
#pragma unroll
        for (int d = 0; d < HID; ++d) o[d] += tv[k] * sW[k * HID + d];
    if (do_relu)
#pragma unroll
        for (int d = 0; d < HID; ++d) o[d] = fmaxf(o[d], 0.f);
    float4* op = (float4*)(out + (size_t)i * HS);
    op[0] = make_float4(o[0], o[1], o[2], o[3]);
    op[1] = make_float4(o[4], o[5], 0.f, 0.f);
}

// ===========================================================================
// pool + output (padded h)
// ===========================================================================
__global__ void pool_kernel(const float* __restrict__ h, const int* __restrict__ batch,
                            float* __restrict__ sums, float* __restrict__ cnts, int N) {
    int i = blockIdx.x * blockDim.x + threadIdx.x;
    int lane = threadIdx.x & 63;
    bool active = (i < N);
    float v[HID];
    int g = -1;
    if (active) {
        g = batch[i];
        float4 h0 = *(const float4*)(h + (size_t)i * HS);
        float4 h1 = *(const float4*)(h + (size_t)i * HS + 4);
        v[0] = h0.x; v[1] = h0.y; v[2] = h0.z; v[3] = h0.w; v[4] = h1.x; v[5] = h1.y;
    } else {
#pragma unroll
        for (int d = 0; d < HID; ++d) v[d] = 0.0f;
    }
    int g0 = __shfl(g, 0);
    bool uniform = __all(active) && __all(g == g0);
    if (uniform) {
#pragma unroll
        for (int d = 0; d < HID; ++d) {
            float s = v[d];
            for (int off = 32; off > 0; off >>= 1) s += __shfl_down(s, off);
            if (lane == 0) atomicAdd(&sums[(size_t)g0 * HID + d], s);
        }
        if (lane == 0) atomicAdd(&cnts[g0], 64.0f);
    } else if (active) {
#pragma unroll
        for (int d = 0; d < HID; ++d) atomicAdd(&sums[(size_t)g * HID + d], v[d]);
        atomicAdd(&cnts[g], 1.0f);
    }
}

__global__ void out_kernel(const float* __restrict__ sums, const float* __restrict__ cnts,
                           const float* __restrict__ Wl, const float* __restrict__ bl,
                           float* __restrict__ out) {
    int gI = blockIdx.x * blockDim.x + threadIdx.x;
    if (gI >= NUM_GRAPHS) return;
    float c = fmaxf(cnts[gI], 1.0f);
    float acc = bl[0];
#pragma unroll
    for (int d = 0; d < HID; ++d) acc += (sums[(size_t)gI * HID + d] / c) * Wl[d];
    out[gI] = acc;
}

// ===========================================================================
extern "C" void kernel_launch(void* const* d_in, const int* in_sizes, int n_in,
                              void* d_out, int out_size, void* d_ws, size_t ws_size,
                              hipStream_t stream) {
    const float* x         = (const float*)d_in[0];
    const int*   eidx      = (const int*)d_in[1];
    const float* edge_attr = (const float*)d_in[2];
    const int*   batch     = (const int*)d_in[3];
    const float* W1 = (const float*)d_in[4];
    const float* b1 = (const float*)d_in[5];
    const float* W2 = (const float*)d_in[6];
    const float* b2 = (const float*)d_in[7];
    const float* W3 = (const float*)d_in[8];
    const float* b3 = (const float*)d_in[9];
    const float* Wl = (const float*)d_in[10];
    const float* bl = (const float*)d_in[11];

    const int N = in_sizes[0] / HID;
    const int E = in_sizes[1] / 2;
    const int* src = eidx;
    const int* dst = eidx + E;

    const int TB = 256;
    const int nbl = (N + TB - 1) / TB;
    const int ebl = (E + TB - 1) / TB;
    const int p1bl = (E + P1_CHUNK - 1) / P1_CHUNK;

    const int NB  = (N + BNODES - 1) >> BSHIFT;           // buckets
    const int cap = ((E / (NB > 0 ? NB : 1)) + 3072 + 1023) & ~1023;
    const long slots = (long)NB * cap;

    char* w = (char*)d_ws;
    size_t off = 0;
    auto alloc = [&](size_t bytes) { void* p = w + off; off += (bytes + 255) & ~(size_t)255; return p; };

    float* hX   = (float*)alloc((size_t)N * HS * sizeof(float));   // 32MB
    float* hA   = (float*)alloc((size_t)N * HS * sizeof(float));   // 32MB
    float* hB   = (float*)alloc((size_t)N * HS * sizeof(float));   // 32MB
    float* sums = (float*)alloc((size_t)NUM_GRAPHS * HID * sizeof(float));
    float* cnts = (float*)alloc((size_t)NUM_GRAPHS * sizeof(float));
    size_t tierDneed = off + (size_t)N * HID * sizeof(float);      // + agg

    float*          ea_perm   = (float*)alloc((size_t)slots * HID * sizeof(float)); // ~324MB
    int*            src_perm  = (int*)alloc((size_t)slots * sizeof(int));           // ~54MB
    unsigned short* dloc_perm = (unsigned short*)alloc((size_t)slots * sizeof(unsigned short)); // ~27MB
    int*            gcursor   = (int*)alloc((size_t)NB * sizeof(int));
    size_t tierAneed = off;

    pad_kernel<<<nbl, TB, 0, stream>>>(x, hX, N);

    if (NB <= MAXNB && ws_size >= tierAneed) {
        // ---- one-time bucket binning ----
        init_gcursor_kernel<<<(NB + TB - 1) / TB, TB, 0, stream>>>(gcursor, NB, cap);
        pass1_kernel<<<p1bl, TB, 0, stream>>>(src, dst, edge_attr, gcursor,
                                              src_perm, dloc_perm, ea_perm, E, cap, NB);

        // ---- bucket-fused layers (no global float atomics, no agg buffer) ----
        layer_kernel<<<NB, TB, 0, stream>>>(hX, ea_perm, src_perm, dloc_perm, gcursor,
                                            W1, b1, hA, N, cap, 1);
        layer_kernel<<<NB, TB, 0, stream>>>(hA, ea_perm, src_perm, dloc_perm, gcursor,
                                            W2, b2, hB, N, cap, 1);
        layer_kernel<<<NB, TB, 0, stream>>>(hB, ea_perm, src_perm, dloc_perm, gcursor,
                                            W3, b3, hA, N, cap, 0);
    } else {
        // ---- tier D: atomic fallback ----
        float* agg = (float*)((char*)w + tierDneed - (size_t)N * HID * sizeof(float));
        const size_t szAgg = (size_t)N * HID * sizeof(float);
        hipMemsetAsync(agg, 0, szAgg, stream);
        edge_kernel<<<ebl, TB, 0, stream>>>(hX, edge_attr, src, dst, agg, E);
        node_kernel<<<nbl, TB, 0, stream>>>(hX, agg, W1, b1, hA, N, 1);
        hipMemsetAsync(agg, 0, szAgg, stream);
        edge_kernel<<<ebl, TB, 0, stream>>>(hA, edge_attr, src, dst, agg, E);
        node_kernel<<<nbl, TB, 0, stream>>>(hA, agg, W2, b2, hB, N, 1);
        hipMemsetAsync(agg, 0, szAgg, stream);
        edge_kernel<<<ebl, TB, 0, stream>>>(hB, edge_attr, src, dst, agg, E);
        node_kernel<<<nbl, TB, 0, stream>>>(hB, agg, W3, b3, hA, N, 0);
    }

    hipMemsetAsync(sums, 0, (size_t)NUM_GRAPHS * HID * sizeof(float), stream);
    hipMemsetAsync(cnts, 0, (size_t)NUM_GRAPHS * sizeof(float), stream);
    pool_kernel<<<nbl, TB, 0, stream>>>(hA, batch, sums, cnts, N);
    out_kernel<<<(NUM_GRAPHS + TB - 1) / TB, TB, 0, stream>>>(sums, cnts, Wl, bl, (float*)d_out);
}

// Round 7
// 1790.778 us; speedup vs baseline: 5.8854x; 1.0464x over previous
//
#include <hip/hip_runtime.h>

#define HID 6
#define HS  8                   // padded row stride (floats) for h buffers
#define NUM_GRAPHS 1000
#define BSHIFT 11
#define BNODES (1 << BSHIFT)    // 2048 nodes per bucket
#define MAXNB 512               // max buckets supported by pass1 LDS
#define P1_CHUNK 4096
#define P1_PERT  16             // P1_CHUNK / 256

// ===========================================================================
// pad x (N x 6) -> hX (N x 8)
// ===========================================================================
__global__ void pad_kernel(const float* __restrict__ x, float* __restrict__ hX, int N) {
    int i = blockIdx.x * blockDim.x + threadIdx.x;
    if (i >= N) return;
    const float2* s = (const float2*)(x + (size_t)i * HID);
    float2 a = s[0], b = s[1], c = s[2];
    float4* o = (float4*)(hX + (size_t)i * HS);
    o[0] = make_float4(a.x, a.y, b.x, b.y);
    o[1] = make_float4(c.x, c.y, 0.f, 0.f);
}

__global__ void init_gcursor_kernel(int* __restrict__ gcursor, int NB, int cap) {
    int b = blockIdx.x * blockDim.x + threadIdx.x;
    if (b < NB) gcursor[b] = b * cap;
}

// ===========================================================================
// pass1: bin edges by dst>>BSHIFT into fixed-capacity bucket regions.
// In-LDS bucket sort of edge ids -> output written in bucket order, so
// payload writes are contiguous runs (line-coalesced). Payload reads hit
// the block's own L2-resident input windows.
// ===========================================================================
__global__ void __launch_bounds__(256) pass1_kernel(
        const int* __restrict__ src, const int* __restrict__ dst,
        const float* __restrict__ ea,
        int* __restrict__ gcursor,
        int* __restrict__ src_perm, unsigned short* __restrict__ dloc_perm,
        float* __restrict__ ea_perm,
        int E, int cap, int NB) {
    __shared__ int hist[MAXNB];
    __shared__ int cnt[MAXNB];
    __shared__ int base[MAXNB];
    __shared__ int lofs[MAXNB];
    __shared__ int pairs[256];
    __shared__ unsigned short slot_eid[P1_CHUNK];
    __shared__ unsigned short slot_b[P1_CHUNK];

    int t = threadIdx.x;
    long e0 = (long)blockIdx.x * P1_CHUNK;
    int count = (int)(((long)E - e0) < P1_CHUNK ? ((long)E - e0) : P1_CHUNK);

    for (int b = t; b < MAXNB; b += 256) { hist[b] = 0; cnt[b] = 0; }
    __syncthreads();

    // phase 1: histogram (b kept in registers)
    int d[P1_PERT];
#pragma unroll
    for (int j = 0; j < P1_PERT; ++j) {
        int le = t + j * 256;
        d[j] = (le < count) ? dst[e0 + le] : -1;
        if (d[j] >= 0) atomicAdd(&hist[d[j] >> BSHIFT], 1);
    }
    __syncthreads();

    // phase 2a: exclusive scan of hist[0..2*256) -> lofs
    {
        int b0 = 2 * t, b1 = 2 * t + 1;
        int s0 = hist[b0], s1 = hist[b1];
        pairs[t] = s0 + s1;
        __syncthreads();
        for (int off = 1; off < 256; off <<= 1) {
            int a = (t >= off) ? pairs[t - off] : 0;
            __syncthreads();
            pairs[t] += a;
            __syncthreads();
        }
        int excl = (t == 0) ? 0 : pairs[t - 1];
        lofs[b0] = excl;
        lofs[b1] = excl + s0;
    }
    // phase 2b: reserve global space per touched bucket
    for (int b = t; b < NB; b += 256) {
        int c = hist[b];
        base[b] = c ? atomicAdd(&gcursor[b], c) : 0;
    }
    __syncthreads();

    // phase 3: rank edges into slots (bucket-sorted order)
#pragma unroll
    for (int j = 0; j < P1_PERT; ++j) {
        if (d[j] < 0) continue;
        int le = t + j * 256;
        int b = d[j] >> BSHIFT;
        int r = atomicAdd(&cnt[b], 1);
        int slot = lofs[b] + r;
        slot_eid[slot] = (unsigned short)le;
        slot_b[slot] = (unsigned short)b;
    }
    __syncthreads();

    // phase 4: walk slots in order -> contiguous writes per bucket run
    for (int s = t; s < count; s += 256) {
        int b = slot_b[s];
        int le = slot_eid[s];
        long e = e0 + le;
        long gpos = (long)base[b] + (s - lofs[b]);
        int dd = dst[e];                       // L2-hot window
        src_perm[gpos] = src[e];               // L2-hot window
        dloc_perm[gpos] = (unsigned short)(dd & (BNODES - 1));
        const float2* sp = (const float2*)(ea + (size_t)e * HID);
        float2 a0 = sp[0], a1 = sp[1], a2 = sp[2];
        float2* o = (float2*)(ea_perm + (size_t)gpos * HID);
        o[0] = a0; o[1] = a1; o[2] = a2;
    }
}

// ===========================================================================
// bucket-fused GINE layer: one WG per bucket; LDS agg for 2048 nodes;
// stream bucket edges, LDS atomicAdd; epilogue = (h+agg)@W+b coalesced.
// ===========================================================================
__global__ void __launch_bounds__(256) layer_kernel(
        const float* __restrict__ h,
        const float* __restrict__ ea_perm,
        const int* __restrict__ src_perm,
        const unsigned short* __restrict__ dloc_perm,
        const int* __restrict__ gcursor,
        const float* __restrict__ W, const float* __restrict__ b,
        float* __restrict__ out, int N, int cap, int do_relu) {
    __shared__ float sagg[BNODES * HID];     // 48 KB
    __shared__ float sW[HID * HID];
    __shared__ float sb[HID];
    int t = threadIdx.x;
    int bk = blockIdx.x;
    if (t < HID * HID) sW[t] = W[t];
    if (t < HID) sb[t] = b[t];
    for (int i = t; i < BNODES * HID; i += 256) sagg[i] = 0.f;
    __syncthreads();

    long kbeg = (long)bk * cap;
    int cnt = gcursor[bk] - (int)((long)bk * cap);

    for (int k = t; k < cnt; k += 256) {
        long kk = kbeg + k;
        int s = src_perm[kk];
        int dl = dloc_perm[kk];
        const float2* ap = (const float2*)(ea_perm + (size_t)kk * HID);
        float2 e0 = ap[0], e1 = ap[1], e2 = ap[2];
        float4 g0 = *(const float4*)(h + (size_t)s * HS);
        float4 g1 = *(const float4*)(h + (size_t)s * HS + 4);
        float* p = sagg + (size_t)dl * HID;
        atomicAdd(p + 0, fmaxf(g0.x + e0.x, 0.f));
        atomicAdd(p + 1, fmaxf(g0.y + e0.y, 0.f));
        atomicAdd(p + 2, fmaxf(g0.z + e1.x, 0.f));
        atomicAdd(p + 3, fmaxf(g0.w + e1.y, 0.f));
        atomicAdd(p + 4, fmaxf(g1.x + e2.x, 0.f));
        atomicAdd(p + 5, fmaxf(g1.y + e2.y, 0.f));
    }
    __syncthreads();

    int nodeBase = bk << BSHIFT;
    for (int n = t; n < BNODES; n += 256) {
        int i = nodeBase + n;
        if (i >= N) break;
        float4 h0 = *(const float4*)(h + (size_t)i * HS);
        float4 h1 = *(const float4*)(h + (size_t)i * HS + 4);
        const float* sp = sagg + (size_t)n * HID;
        float tv[HID];
        tv[0] = h0.x + sp[0]; tv[1] = h0.y + sp[1]; tv[2] = h0.z + sp[2];
        tv[3] = h0.w + sp[3]; tv[4] = h1.x + sp[4]; tv[5] = h1.y + sp[5];
        float o[HID];
#pragma unroll
        for (int dd = 0; dd < HID; ++dd) o[dd] = sb[dd];
#pragma unroll
        for (int k = 0; k < HID; ++k)
#pragma unroll
            for (int dd = 0; dd < HID; ++dd) o[dd] += tv[k] * sW[k * HID + dd];
        if (do_relu)
#pragma unroll
            for (int dd = 0; dd < HID; ++dd) o[dd] = fmaxf(o[dd], 0.f);
        float4* op = (float4*)(out + (size_t)i * HS);
        op[0] = make_float4(o[0], o[1], o[2], o[3]);
        op[1] = make_float4(o[4], o[5], 0.f, 0.f);
    }
}

// ===========================================================================
// tier D fallback: atomic edge pass + node update (padded layouts)
// ===========================================================================
__global__ void edge_kernel(const float* __restrict__ h, const float* __restrict__ edge_attr,
                            const int* __restrict__ src, const int* __restrict__ dst,
                            float* __restrict__ agg, int E) {
    long e = (long)blockIdx.x * blockDim.x + threadIdx.x;
    if (e >= E) return;
    int s = src[e], d = dst[e];
    const float2* ea = (const float2*)(edge_attr + (size_t)e * HID);
    float4 g0 = *(const float4*)(h + (size_t)s * HS);
    float4 g1 = *(const float4*)(h + (size_t)s * HS + 4);
    float2 a0 = ea[0], a1 = ea[1], a2 = ea[2];
    float* ag = agg + (size_t)d * HID;
    atomicAdd(ag + 0, fmaxf(g0.x + a0.x, 0.f));
    atomicAdd(ag + 1, fmaxf(g0.y + a0.y, 0.f));
    atomicAdd(ag + 2, fmaxf(g0.z + a1.x, 0.f));
    atomicAdd(ag + 3, fmaxf(g0.w + a1.y, 0.f));
    atomicAdd(ag + 4, fmaxf(g1.x + a2.x, 0.f));
    atomicAdd(ag + 5, fmaxf(g1.y + a2.y, 0.f));
}

__global__ void node_kernel(const float* __restrict__ h, const float* __restrict__ agg,
                            const float* __restrict__ W, const float* __restrict__ b,
                            float* __restrict__ out, int N, int do_relu) {
    __shared__ float sW[HID * HID];
    __shared__ float sb[HID];
    if (threadIdx.x < HID * HID) sW[threadIdx.x] = W[threadIdx.x];
    if (threadIdx.x < HID) sb[threadIdx.x] = b[threadIdx.x];
    __syncthreads();
    int i = blockIdx.x * blockDim.x + threadIdx.x;
    if (i >= N) return;
    float4 h0 = *(const float4*)(h + (size_t)i * HS);
    float4 h1 = *(const float4*)(h + (size_t)i * HS + 4);
    const float2* ap = (const float2*)(agg + (size_t)i * HID);
    float2 g0 = ap[0], g1 = ap[1], g2 = ap[2];
    float tv[HID];
    tv[0] = h0.x + g0.x; tv[1] = h0.y + g0.y;
    tv[2] = h0.z + g1.x; tv[3] = h0.w + g1.y;
    tv[4] = h1.x + g2.x; tv[5] = h1.y + g2.y;
    float o[HID];
#pragma unroll
    for (int d = 0; d < HID; ++d) o[d] = sb[d];
#pragma unroll
    for (int k = 0; k < HID; ++k)
#pragma unroll
        for (int d = 0; d < HID; ++d) o[d] += tv[k] * sW[k * HID + d];
    if (do_relu)
#pragma unroll
        for (int d = 0; d < HID; ++d) o[d] = fmaxf(o[d], 0.f);
    float4* op = (float4*)(out + (size_t)i * HS);
    op[0] = make_float4(o[0], o[1], o[2], o[3]);
    op[1] = make_float4(o[4], o[5], 0.f, 0.f);
}

// ===========================================================================
// pool + output (padded h)
// ===========================================================================
__global__ void pool_kernel(const float* __restrict__ h, const int* __restrict__ batch,
                            float* __restrict__ sums, float* __restrict__ cnts, int N) {
    int i = blockIdx.x * blockDim.x + threadIdx.x;
    int lane = threadIdx.x & 63;
    bool active = (i < N);
    float v[HID];
    int g = -1;
    if (active) {
        g = batch[i];
        float4 h0 = *(const float4*)(h + (size_t)i * HS);
        float4 h1 = *(const float4*)(h + (size_t)i * HS + 4);
        v[0] = h0.x; v[1] = h0.y; v[2] = h0.z; v[3] = h0.w; v[4] = h1.x; v[5] = h1.y;
    } else {
#pragma unroll
        for (int d = 0; d < HID; ++d) v[d] = 0.0f;
    }
    int g0 = __shfl(g, 0);
    bool uniform = __all(active) && __all(g == g0);
    if (uniform) {
#pragma unroll
        for (int d = 0; d < HID; ++d) {
            float s = v[d];
            for (int off = 32; off > 0; off >>= 1) s += __shfl_down(s, off);
            if (lane == 0) atomicAdd(&sums[(size_t)g0 * HID + d], s);
        }
        if (lane == 0) atomicAdd(&cnts[g0], 64.0f);
    } else if (active) {
#pragma unroll
        for (int d = 0; d < HID; ++d) atomicAdd(&sums[(size_t)g * HID + d], v[d]);
        atomicAdd(&cnts[g], 1.0f);
    }
}

__global__ void out_kernel(const float* __restrict__ sums, const float* __restrict__ cnts,
                           const float* __restrict__ Wl, const float* __restrict__ bl,
                           float* __restrict__ out) {
    int gI = blockIdx.x * blockDim.x + threadIdx.x;
    if (gI >= NUM_GRAPHS) return;
    float c = fmaxf(cnts[gI], 1.0f);
    float acc = bl[0];
#pragma unroll
    for (int d = 0; d < HID; ++d) acc += (sums[(size_t)gI * HID + d] / c) * Wl[d];
    out[gI] = acc;
}

// ===========================================================================
extern "C" void kernel_launch(void* const* d_in, const int* in_sizes, int n_in,
                              void* d_out, int out_size, void* d_ws, size_t ws_size,
                              hipStream_t stream) {
    const float* x         = (const float*)d_in[0];
    const int*   eidx      = (const int*)d_in[1];
    const float* edge_attr = (const float*)d_in[2];
    const int*   batch     = (const int*)d_in[3];
    const float* W1 = (const float*)d_in[4];
    const float* b1 = (const float*)d_in[5];
    const float* W2 = (const float*)d_in[6];
    const float* b2 = (const float*)d_in[7];
    const float* W3 = (const float*)d_in[8];
    const float* b3 = (const float*)d_in[9];
    const float* Wl = (const float*)d_in[10];
    const float* bl = (const float*)d_in[11];

    const int N = in_sizes[0] / HID;
    const int E = in_sizes[1] / 2;
    const int* src = eidx;
    const int* dst = eidx + E;

    const int TB = 256;
    const int nbl = (N + TB - 1) / TB;
    const int ebl = (E + TB - 1) / TB;
    const int p1bl = (E + P1_CHUNK - 1) / P1_CHUNK;

    const int NB  = (N + BNODES - 1) >> BSHIFT;           // buckets
    const int cap = ((E / (NB > 0 ? NB : 1)) + 3072 + 1023) & ~1023;
    const long slots = (long)NB * cap;

    char* w = (char*)d_ws;
    size_t off = 0;
    auto alloc = [&](size_t bytes) { void* p = w + off; off += (bytes + 255) & ~(size_t)255; return p; };

    float* hX   = (float*)alloc((size_t)N * HS * sizeof(float));   // 32MB
    float* hA   = (float*)alloc((size_t)N * HS * sizeof(float));   // 32MB
    float* hB   = (float*)alloc((size_t)N * HS * sizeof(float));   // 32MB
    float* sums = (float*)alloc((size_t)NUM_GRAPHS * HID * sizeof(float));
    float* cnts = (float*)alloc((size_t)NUM_GRAPHS * sizeof(float));
    size_t tierDneed = off + (size_t)N * HID * sizeof(float);      // + agg

    float*          ea_perm   = (float*)alloc((size_t)slots * HID * sizeof(float)); // ~324MB
    int*            src_perm  = (int*)alloc((size_t)slots * sizeof(int));           // ~54MB
    unsigned short* dloc_perm = (unsigned short*)alloc((size_t)slots * sizeof(unsigned short)); // ~27MB
    int*            gcursor   = (int*)alloc((size_t)NB * sizeof(int));
    size_t tierAneed = off;

    pad_kernel<<<nbl, TB, 0, stream>>>(x, hX, N);

    if (NB <= MAXNB && ws_size >= tierAneed) {
        // ---- one-time bucket binning (LDS-sorted, coalesced writes) ----
        init_gcursor_kernel<<<(NB + TB - 1) / TB, TB, 0, stream>>>(gcursor, NB, cap);
        pass1_kernel<<<p1bl, TB, 0, stream>>>(src, dst, edge_attr, gcursor,
                                              src_perm, dloc_perm, ea_perm, E, cap, NB);

        // ---- bucket-fused layers (no global float atomics, no agg buffer) ----
        layer_kernel<<<NB, TB, 0, stream>>>(hX, ea_perm, src_perm, dloc_perm, gcursor,
                                            W1, b1, hA, N, cap, 1);
        layer_kernel<<<NB, TB, 0, stream>>>(hA, ea_perm, src_perm, dloc_perm, gcursor,
                                            W2, b2, hB, N, cap, 1);
        layer_kernel<<<NB, TB, 0, stream>>>(hB, ea_perm, src_perm, dloc_perm, gcursor,
                                            W3, b3, hA, N, cap, 0);
    } else {
        // ---- tier D: atomic fallback ----
        float* agg = (float*)((char*)w + tierDneed - (size_t)N * HID * sizeof(float));
        const size_t szAgg = (size_t)N * HID * sizeof(float);
        hipMemsetAsync(agg, 0, szAgg, stream);
        edge_kernel<<<ebl, TB, 0, stream>>>(hX, edge_attr, src, dst, agg, E);
        node_kernel<<<nbl, TB, 0, stream>>>(hX, agg, W1, b1, hA, N, 1);
        hipMemsetAsync(agg, 0, szAgg, stream);
        edge_kernel<<<ebl, TB, 0, stream>>>(hA, edge_attr, src, dst, agg, E);
        node_kernel<<<nbl, TB, 0, stream>>>(hA, agg, W2, b2, hB, N, 1);
        hipMemsetAsync(agg, 0, szAgg, stream);
        edge_kernel<<<ebl, TB, 0, stream>>>(hB, edge_attr, src, dst, agg, E);
        node_kernel<<<nbl, TB, 0, stream>>>(hB, agg, W3, b3, hA, N, 0);
    }

    hipMemsetAsync(sums, 0, (size_t)NUM_GRAPHS * HID * sizeof(float), stream);
    hipMemsetAsync(cnts, 0, (size_t)NUM_GRAPHS * sizeof(float), stream);
    pool_kernel<<<nbl, TB, 0, stream>>>(hA, batch, sums, cnts, N);
    out_kernel<<<(NUM_GRAPHS + TB - 1) / TB, TB, 0, stream>>>(sums, cnts, Wl, bl, (float*)d_out);
}

// Round 8
// 1494.896 us; speedup vs baseline: 7.0503x; 1.1979x over previous
//
#include <hip/hip_runtime.h>
#include <hip/hip_fp16.h>

#define HID 6
#define HS  8                   // padded row stride (floats) for h buffers
#define NUM_GRAPHS 1000
#define BSHIFT 11
#define BNODES (1 << BSHIFT)    // 2048 nodes per bucket
#define MAXNB 512               // max buckets
#define P1_CHUNK 3072
#define P1_PERT  12             // P1_CHUNK / 256

__device__ __forceinline__ unsigned pk2(float a, float b) {
    __half2 h = __floats2half2_rn(a, b);
    return *(unsigned*)&h;
}
__device__ __forceinline__ float2 up2(unsigned u) {
    __half2 h = *(__half2*)&u;
    return __half22float2(h);
}

// ===========================================================================
// pad x (N x 6) -> hX (N x 8)
// ===========================================================================
__global__ void pad_kernel(const float* __restrict__ x, float* __restrict__ hX, int N) {
    int i = blockIdx.x * blockDim.x + threadIdx.x;
    if (i >= N) return;
    const float2* s = (const float2*)(x + (size_t)i * HID);
    float2 a = s[0], b = s[1], c = s[2];
    float4* o = (float4*)(hX + (size_t)i * HS);
    o[0] = make_float4(a.x, a.y, b.x, b.y);
    o[1] = make_float4(c.x, c.y, 0.f, 0.f);
}

__global__ void init_gcursor_kernel(int* __restrict__ gcursor, int NB, int cap) {
    int b = blockIdx.x * blockDim.x + threadIdx.x;
    if (b < NB) gcursor[b] = b * cap;
}

// ===========================================================================
// pass1: bin edges by dst>>BSHIFT into fixed-capacity bucket regions.
// All global reads AND writes coalesced: LDS permute of 16B packed records.
//   ph1: coalesced dst read -> LDS hist
//   ph2: LDS scan + one global atomic per (block,bucket)
//   ph3: coalesced src/ea read -> pack fp16 -> LDS scatter at slot
//   ph4: sequential LDS read -> contiguous global runs per bucket
// ===========================================================================
__global__ void __launch_bounds__(256) pass1_kernel(
        const int* __restrict__ src, const int* __restrict__ dst,
        const float* __restrict__ ea,
        int* __restrict__ gcursor,
        uint4* __restrict__ packed_perm,
        int E, int cap, int NB) {
    __shared__ uint4 pay[P1_CHUNK];                  // 48 KB
    __shared__ unsigned short sb_[P1_CHUNK];         // 6 KB
    __shared__ int hist[MAXNB];
    __shared__ int cnt[MAXNB];
    __shared__ int base[MAXNB];
    __shared__ int lofs[MAXNB];
    __shared__ int pairs[256];

    int t = threadIdx.x;
    long e0 = (long)blockIdx.x * P1_CHUNK;
    long rem = (long)E - e0;
    int count = (int)(rem < P1_CHUNK ? rem : P1_CHUNK);

    for (int b = t; b < MAXNB; b += 256) { hist[b] = 0; cnt[b] = 0; }
    __syncthreads();

    // phase 1: histogram (dst kept in registers)
    int d[P1_PERT];
#pragma unroll
    for (int j = 0; j < P1_PERT; ++j) {
        int le = t + j * 256;
        d[j] = (le < count) ? dst[e0 + le] : -1;
        if (d[j] >= 0) atomicAdd(&hist[d[j] >> BSHIFT], 1);
    }
    __syncthreads();

    // phase 2a: exclusive scan of hist[0..512) -> lofs
    {
        int b0 = 2 * t, b1 = 2 * t + 1;
        int s0 = hist[b0], s1 = hist[b1];
        pairs[t] = s0 + s1;
        __syncthreads();
        for (int off = 1; off < 256; off <<= 1) {
            int a = (t >= off) ? pairs[t - off] : 0;
            __syncthreads();
            pairs[t] += a;
            __syncthreads();
        }
        int excl = (t == 0) ? 0 : pairs[t - 1];
        lofs[b0] = excl;
        lofs[b1] = excl + s0;
    }
    // phase 2b: reserve global space per touched bucket
    for (int b = t; b < NB; b += 256) {
        int c = hist[b];
        base[b] = c ? atomicAdd(&gcursor[b], c) : 0;
    }
    __syncthreads();

    // phase 3: coalesced payload read -> pack -> LDS scatter at slot
#pragma unroll
    for (int j = 0; j < P1_PERT; ++j) {
        int le = t + j * 256;
        if (le >= count) continue;
        int dd = d[j];
        int b = dd >> BSHIFT;
        long e = e0 + le;
        int s = src[e];
        const float2* ep = (const float2*)(ea + (size_t)e * HID);
        float2 A = ep[0], B = ep[1], C = ep[2];
        uint4 p;
        p.x = pk2(A.x, A.y);
        p.y = pk2(B.x, B.y);
        p.z = pk2(C.x, C.y);
        p.w = (unsigned)s | ((unsigned)(dd & (BNODES - 1)) << 20);
        int r = atomicAdd(&cnt[b], 1);
        int slot = lofs[b] + r;
        pay[slot] = p;
        sb_[slot] = (unsigned short)b;
    }
    __syncthreads();

    // phase 4: sequential LDS read -> contiguous global runs
    for (int s2 = t; s2 < count; s2 += 256) {
        int b = sb_[s2];
        long gpos = (long)base[b] + (s2 - lofs[b]);
        packed_perm[gpos] = pay[s2];
    }
}

// ===========================================================================
// bucket-fused GINE layer: one WG per bucket; LDS agg for 2048 nodes;
// one uint4 read per edge; LDS atomicAdd; coalesced epilogue.
// ===========================================================================
__global__ void __launch_bounds__(256) layer_kernel(
        const float* __restrict__ h,
        const uint4* __restrict__ packed,
        const int* __restrict__ gcursor,
        const float* __restrict__ W, const float* __restrict__ b,
        float* __restrict__ out, int N, int cap, int do_relu) {
    __shared__ float sagg[BNODES * HID];     // 48 KB
    __shared__ float sW[HID * HID];
    __shared__ float sb[HID];
    int t = threadIdx.x;
    int bk = blockIdx.x;
    if (t < HID * HID) sW[t] = W[t];
    if (t < HID) sb[t] = b[t];
    for (int i = t; i < BNODES * HID; i += 256) sagg[i] = 0.f;
    __syncthreads();

    long kbeg = (long)bk * cap;
    int cnt = gcursor[bk] - (int)kbeg;

    for (int k = t; k < cnt; k += 256) {
        uint4 p = packed[kbeg + k];
        int s  = p.w & 0xFFFFF;
        int dl = p.w >> 20;
        float2 e01 = up2(p.x), e23 = up2(p.y), e45 = up2(p.z);
        float4 g0 = *(const float4*)(h + (size_t)s * HS);
        float4 g1 = *(const float4*)(h + (size_t)s * HS + 4);
        float* pp = sagg + (size_t)dl * HID;
        atomicAdd(pp + 0, fmaxf(g0.x + e01.x, 0.f));
        atomicAdd(pp + 1, fmaxf(g0.y + e01.y, 0.f));
        atomicAdd(pp + 2, fmaxf(g0.z + e23.x, 0.f));
        atomicAdd(pp + 3, fmaxf(g0.w + e23.y, 0.f));
        atomicAdd(pp + 4, fmaxf(g1.x + e45.x, 0.f));
        atomicAdd(pp + 5, fmaxf(g1.y + e45.y, 0.f));
    }
    __syncthreads();

    int nodeBase = bk << BSHIFT;
    for (int n = t; n < BNODES; n += 256) {
        int i = nodeBase + n;
        if (i >= N) break;
        float4 h0 = *(const float4*)(h + (size_t)i * HS);
        float4 h1 = *(const float4*)(h + (size_t)i * HS + 4);
        const float* sp = sagg + (size_t)n * HID;
        float tv[HID];
        tv[0] = h0.x + sp[0]; tv[1] = h0.y + sp[1]; tv[2] = h0.z + sp[2];
        tv[3] = h0.w + sp[3]; tv[4] = h1.x + sp[4]; tv[5] = h1.y + sp[5];
        float o[HID];
#pragma unroll
        for (int dd = 0; dd < HID; ++dd) o[dd] = sb[dd];
#pragma unroll
        for (int k = 0; k < HID; ++k)
#pragma unroll
            for (int dd = 0; dd < HID; ++dd) o[dd] += tv[k] * sW[k * HID + dd];
        if (do_relu)
#pragma unroll
            for (int dd = 0; dd < HID; ++dd) o[dd] = fmaxf(o[dd], 0.f);
        float4* op = (float4*)(out + (size_t)i * HS);
        op[0] = make_float4(o[0], o[1], o[2], o[3]);
        op[1] = make_float4(o[4], o[5], 0.f, 0.f);
    }
}

// ===========================================================================
// tier D fallback: atomic edge pass + node update (padded layouts)
// ===========================================================================
__global__ void edge_kernel(const float* __restrict__ h, const float* __restrict__ edge_attr,
                            const int* __restrict__ src, const int* __restrict__ dst,
                            float* __restrict__ agg, int E) {
    long e = (long)blockIdx.x * blockDim.x + threadIdx.x;
    if (e >= E) return;
    int s = src[e], d = dst[e];
    const float2* ea = (const float2*)(edge_attr + (size_t)e * HID);
    float4 g0 = *(const float4*)(h + (size_t)s * HS);
    float4 g1 = *(const float4*)(h + (size_t)s * HS + 4);
    float2 a0 = ea[0], a1 = ea[1], a2 = ea[2];
    float* ag = agg + (size_t)d * HID;
    atomicAdd(ag + 0, fmaxf(g0.x + a0.x, 0.f));
    atomicAdd(ag + 1, fmaxf(g0.y + a0.y, 0.f));
    atomicAdd(ag + 2, fmaxf(g0.z + a1.x, 0.f));
    atomicAdd(ag + 3, fmaxf(g0.w + a1.y, 0.f));
    atomicAdd(ag + 4, fmaxf(g1.x + a2.x, 0.f));
    atomicAdd(ag + 5, fmaxf(g1.y + a2.y, 0.f));
}

__global__ void node_kernel(const float* __restrict__ h, const float* __restrict__ agg,
                            const float* __restrict__ W, const float* __restrict__ b,
                            float* __restrict__ out, int N, int do_relu) {
    __shared__ float sW[HID * HID];
    __shared__ float sb[HID];
    if (threadIdx.x < HID * HID) sW[threadIdx.x] = W[threadIdx.x];
    if (threadIdx.x < HID) sb[threadIdx.x] = b[threadIdx.x];
    __syncthreads();
    int i = blockIdx.x * blockDim.x + threadIdx.x;
    if (i >= N) return;
    float4 h0 = *(const float4*)(h + (size_t)i * HS);
    float4 h1 = *(const float4*)(h + (size_t)i * HS + 4);
    const float2* ap = (const float2*)(agg + (size_t)i * HID);
    float2 g0 = ap[0], g1 = ap[1], g2 = ap[2];
    float tv[HID];
    tv[0] = h0.x + g0.x; tv[1] = h0.y + g0.y;
    tv[2] = h0.z + g1.x; tv[3] = h0.w + g1.y;
    tv[4] = h1.x + g2.x; tv[5] = h1.y + g2.y;
    float o[HID];
#pragma unroll
    for (int d = 0; d < HID; ++d) o[d] = sb[d];
#pragma unroll
    for (int k = 0; k < HID; ++k)
#pragma unroll
        for (int d = 0; d < HID; ++d) o[d] += tv[k] * sW[k * HID + d];
    if (do_relu)
#pragma unroll
        for (int d = 0; d < HID; ++d) o[d] = fmaxf(o[d], 0.f);
    float4* op = (float4*)(out + (size_t)i * HS);
    op[0] = make_float4(o[0], o[1], o[2], o[3]);
    op[1] = make_float4(o[4], o[5], 0.f, 0.f);
}

// ===========================================================================
// pool + output (padded h)
// ===========================================================================
__global__ void pool_kernel(const float* __restrict__ h, const int* __restrict__ batch,
                            float* __restrict__ sums, float* __restrict__ cnts, int N) {
    int i = blockIdx.x * blockDim.x + threadIdx.x;
    int lane = threadIdx.x & 63;
    bool active = (i < N);
    float v[HID];
    int g = -1;
    if (active) {
        g = batch[i];
        float4 h0 = *(const float4*)(h + (size_t)i * HS);
        float4 h1 = *(const float4*)(h + (size_t)i * HS + 4);
        v[0] = h0.x; v[1] = h0.y; v[2] = h0.z; v[3] = h0.w; v[4] = h1.x; v[5] = h1.y;
    } else {
#pragma unroll
        for (int d = 0; d < HID; ++d) v[d] = 0.0f;
    }
    int g0 = __shfl(g, 0);
    bool uniform = __all(active) && __all(g == g0);
    if (uniform) {
#pragma unroll
        for (int d = 0; d < HID; ++d) {
            float s = v[d];
            for (int off = 32; off > 0; off >>= 1) s += __shfl_down(s, off);
            if (lane == 0) atomicAdd(&sums[(size_t)g0 * HID + d], s);
        }
        if (lane == 0) atomicAdd(&cnts[g0], 64.0f);
    } else if (active) {
#pragma unroll
        for (int d = 0; d < HID; ++d) atomicAdd(&sums[(size_t)g * HID + d], v[d]);
        atomicAdd(&cnts[g], 1.0f);
    }
}

__global__ void out_kernel(const float* __restrict__ sums, const float* __restrict__ cnts,
                           const float* __restrict__ Wl, const float* __restrict__ bl,
                           float* __restrict__ out) {
    int gI = blockIdx.x * blockDim.x + threadIdx.x;
    if (gI >= NUM_GRAPHS) return;
    float c = fmaxf(cnts[gI], 1.0f);
    float acc = bl[0];
#pragma unroll
    for (int d = 0; d < HID; ++d) acc += (sums[(size_t)gI * HID + d] / c) * Wl[d];
    out[gI] = acc;
}

// ===========================================================================
extern "C" void kernel_launch(void* const* d_in, const int* in_sizes, int n_in,
                              void* d_out, int out_size, void* d_ws, size_t ws_size,
                              hipStream_t stream) {
    const float* x         = (const float*)d_in[0];
    const int*   eidx      = (const int*)d_in[1];
    const float* edge_attr = (const float*)d_in[2];
    const int*   batch     = (const int*)d_in[3];
    const float* W1 = (const float*)d_in[4];
    const float* b1 = (const float*)d_in[5];
    const float* W2 = (const float*)d_in[6];
    const float* b2 = (const float*)d_in[7];
    const float* W3 = (const float*)d_in[8];
    const float* b3 = (const float*)d_in[9];
    const float* Wl = (const float*)d_in[10];
    const float* bl = (const float*)d_in[11];

    const int N = in_sizes[0] / HID;
    const int E = in_sizes[1] / 2;
    const int* src = eidx;
    const int* dst = eidx + E;

    const int TB = 256;
    const int nbl = (N + TB - 1) / TB;
    const int ebl = (E + TB - 1) / TB;
    const int p1bl = (E + P1_CHUNK - 1) / P1_CHUNK;

    const int NB  = (N + BNODES - 1) >> BSHIFT;           // buckets
    const int cap = ((E / (NB > 0 ? NB : 1)) + 3072 + 1023) & ~1023;
    const long slots = (long)NB * cap + 4096;             // + safety pad

    char* w = (char*)d_ws;
    size_t off = 0;
    auto alloc = [&](size_t bytes) { void* p = w + off; off += (bytes + 255) & ~(size_t)255; return p; };

    float* hX   = (float*)alloc((size_t)N * HS * sizeof(float));   // 32MB
    float* hA   = (float*)alloc((size_t)N * HS * sizeof(float));   // 32MB
    float* hB   = (float*)alloc((size_t)N * HS * sizeof(float));   // 32MB
    float* sums = (float*)alloc((size_t)NUM_GRAPHS * HID * sizeof(float));
    float* cnts = (float*)alloc((size_t)NUM_GRAPHS * sizeof(float));
    size_t tierDneed = off + (size_t)N * HID * sizeof(float);      // + agg

    uint4* packed_perm = (uint4*)alloc((size_t)slots * sizeof(uint4));  // ~220MB
    int*   gcursor     = (int*)alloc((size_t)NB * sizeof(int));
    size_t tierAneed = off;

    pad_kernel<<<nbl, TB, 0, stream>>>(x, hX, N);

    if (NB <= MAXNB && N < (1 << 20) && ws_size >= tierAneed) {
        // ---- one-time binning: coalesced reads AND writes (LDS permute) ----
        init_gcursor_kernel<<<(NB + TB - 1) / TB, TB, 0, stream>>>(gcursor, NB, cap);
        pass1_kernel<<<p1bl, TB, 0, stream>>>(src, dst, edge_attr, gcursor,
                                              packed_perm, E, cap, NB);

        // ---- bucket-fused layers ----
        layer_kernel<<<NB, TB, 0, stream>>>(hX, packed_perm, gcursor, W1, b1, hA, N, cap, 1);
        layer_kernel<<<NB, TB, 0, stream>>>(hA, packed_perm, gcursor, W2, b2, hB, N, cap, 1);
        layer_kernel<<<NB, TB, 0, stream>>>(hB, packed_perm, gcursor, W3, b3, hA, N, cap, 0);
    } else {
        // ---- tier D: atomic fallback ----
        float* agg = (float*)((char*)w + tierDneed - (size_t)N * HID * sizeof(float));
        const size_t szAgg = (size_t)N * HID * sizeof(float);
        hipMemsetAsync(agg, 0, szAgg, stream);
        edge_kernel<<<ebl, TB, 0, stream>>>(hX, edge_attr, src, dst, agg, E);
        node_kernel<<<nbl, TB, 0, stream>>>(hX, agg, W1, b1, hA, N, 1);
        hipMemsetAsync(agg, 0, szAgg, stream);
        edge_kernel<<<ebl, TB, 0, stream>>>(hA, edge_attr, src, dst, agg, E);
        node_kernel<<<nbl, TB, 0, stream>>>(hA, agg, W2, b2, hB, N, 1);
        hipMemsetAsync(agg, 0, szAgg, stream);
        edge_kernel<<<ebl, TB, 0, stream>>>(hB, edge_attr, src, dst, agg, E);
        node_kernel<<<nbl, TB, 0, stream>>>(hB, agg, W3, b3, hA, N, 0);
    }

    hipMemsetAsync(sums, 0, (size_t)NUM_GRAPHS * HID * sizeof(float), stream);
    hipMemsetAsync(cnts, 0, (size_t)NUM_GRAPHS * sizeof(float), stream);
    pool_kernel<<<nbl, TB, 0, stream>>>(hA, batch, sums, cnts, N);
    out_kernel<<<(NUM_GRAPHS + TB - 1) / TB, TB, 0, stream>>>(sums, cnts, Wl, bl, (float*)d_out);
}